// Round 6
// baseline (281.035 us; speedup 1.0000x reference)
//
#include <hip/hip_runtime.h>
#include <hip/hip_bf16.h>
#include <math.h>

#define B 8
#define N 2048
#define C 16
#define HID 128
#define NRF 16384      // 128*128
#define MAXLEN 8
#define MAXCH 2048     // max chains per batch (<= N)

__device__ __forceinline__ float sigf(float x) { return 1.f / (1.f + expf(-x)); }

// ---------------- setup: init counters + transpose weights + bias ----------
__global__ __launch_bounds__(256) void k_setup(
    const float* __restrict__ w_ih, const float* __restrict__ w_hh,
    const float* __restrict__ b_ih, const float* __restrict__ b_hh,
    float* __restrict__ w_ih_T, float* __restrict__ w_hh_T,
    float* __restrict__ biassum, int* __restrict__ cntrf,
    int* __restrict__ map, int* __restrict__ cnt,
    int* __restrict__ m2cnt, int* __restrict__ m3cnt) {
    int i = blockIdx.x * blockDim.x + threadIdx.x;   // 512 blocks -> B*NRF
    cntrf[i] = 0;
    map[i] = -1;
    if (i < B) cnt[i] = 0;
    if (i < 128) { m2cnt[i] = 0; m3cnt[i] = 0; }
    if (i < C * 512) {                 // w_ih_T[c][j] = w_ih[j][c]
        int c = i >> 9, j = i & 511;
        w_ih_T[i] = w_ih[j * C + c];
    }
    if (i < HID * 512) {               // w_hh_T[k][j] = w_hh[j][k]
        int k = i >> 9, j = i & 511;
        w_hh_T[i] = w_hh[j * HID + k];
    }
    if (i < 512) biassum[i] = b_ih[i] + b_hh[i];
}

// ---------------- build: bucket events by (b, rf) ----------------
// R1 lesson: ONE device atomic on cnt[b] per block (contended same-address
// atomics ~98 ns each).
__global__ __launch_bounds__(256) void k_build(
    const int* __restrict__ coords, int* __restrict__ cntrf,
    int* __restrict__ map, int* __restrict__ cnt,
    int* __restrict__ chainrf, int* __restrict__ slots) {
    int tid = threadIdx.x;
    int idx = blockIdx.x * 256 + tid;   // grid exactly B*N (64 blocks)
    int b = idx >> 11;                  // uniform within block
    int n = idx & (N - 1);
    int x = coords[idx * 2 + 0];
    int y = coords[idx * 2 + 1];
    int rf = y * 128 + x;
    int pos = atomicAdd(&cntrf[b * NRF + rf], 1);
    if (pos < MAXLEN) slots[(b * NRF + rf) * MAXLEN + pos] = n;
    __shared__ int lcnt, lbase;
    if (tid == 0) lcnt = 0;
    __syncthreads();
    int r = -1;
    if (pos == 0) r = atomicAdd(&lcnt, 1);
    __syncthreads();
    if (tid == 0) lbase = atomicAdd(&cnt[b], lcnt);   // 1 per block
    __syncthreads();
    if (pos == 0) {
        int k = lbase + r;
        chainrf[b * MAXCH + k] = rf;
        map[b * NRF + rf] = k;
    }
}

// ---------------- first: step-0 for EVERY chain + classification -----------
// c_prev = 0 -> f-gate dead. Writes h always, c only for len>=2. Sorts slots
// into time order for multi chains. Registers len>=2 / len>=3 chains into
// per-batch segmented lists (<=32 contenders per counter).
__global__ __launch_bounds__(256) void k_first(
    const float* __restrict__ features, const float* __restrict__ w_ih_T,
    const float* __restrict__ biassum, const int* __restrict__ cnt,
    const int* __restrict__ chainrf, const int* __restrict__ cntrf,
    int* __restrict__ slots, float* __restrict__ hfin, float* __restrict__ cfin,
    int* __restrict__ m2cnt, int* __restrict__ mlist2,
    int* __restrict__ m3cnt, int* __restrict__ mlist3) {
    int tid = threadIdx.x;
    int lane = tid & 63, w = tid >> 6;
    int bb = blockIdx.x >> 5;           // 32 blocks per batch, grid = 256
    __shared__ int l_idx[64], l_len[64], l_ev0[64];
    __shared__ int lm2[64], lm3[64];
    __shared__ int l_n, l_m2, l_m3, l_b2, l_b3;
    if (tid == 0) { l_n = 0; l_m2 = 0; l_m3 = 0; }
    __syncthreads();
    if (tid < 64) {                     // parallel slot scan
        int idx = blockIdx.x * 64 + tid;
        int j = idx & (MAXCH - 1);
        if (j < cnt[bb]) {
            int bn = bb * NRF + chainrf[idx];
            int len = cntrf[bn];
            if (len > MAXLEN) len = MAXLEN;
            int* sl = slots + (size_t)bn * MAXLEN;
            int ev0;
            if (len >= 2) {             // time-sort slots, write back
                int ev[MAXLEN];
#pragma unroll
                for (int t = 0; t < MAXLEN; t++) {
                    int v = sl[t];
                    ev[t] = (t < len) ? v : 0x7fffffff;
                }
#pragma unroll
                for (int a = 0; a < MAXLEN; a++)
#pragma unroll
                    for (int q = 0; q < MAXLEN - 1; q++) {
                        int u = ev[q], v = ev[q + 1];
                        ev[q] = min(u, v);
                        ev[q + 1] = max(u, v);
                    }
                for (int t = 0; t < len; t++) sl[t] = ev[t];
                ev0 = ev[0];
                int r2 = atomicAdd(&l_m2, 1);
                lm2[r2] = idx;
                if (len >= 3) { int r3 = atomicAdd(&l_m3, 1); lm3[r3] = idx; }
            } else {
                ev0 = sl[0];
            }
            int r = atomicAdd(&l_n, 1);
            l_idx[r] = idx; l_len[r] = len; l_ev0[r] = ev0;
        }
    }
    __syncthreads();
    if (tid == 0 && l_m2 > 0) l_b2 = atomicAdd(&m2cnt[bb * 16], l_m2);
    if (tid == 1 && l_m3 > 0) l_b3 = atomicAdd(&m3cnt[bb * 16], l_m3);
    __syncthreads();
    if (tid < l_m2) { int p = l_b2 + tid; if (p < 256) mlist2[bb * 256 + p] = lm2[tid]; }
    if (tid < l_m3) { int p = l_b3 + tid; if (p < 64)  mlist3[bb * 64 + p]  = lm3[tid]; }
    int nn = l_n;
    if (nn == 0) return;
    // register-cache the 6 live gate columns of w_ih_T (f dead at step 0)
    float wi0[16], wi1[16], wg0[16], wg1[16], wo0[16], wo1[16];
#pragma unroll
    for (int c2 = 0; c2 < 16; c2++) {
        wi0[c2] = w_ih_T[c2 * 512 + lane];
        wi1[c2] = w_ih_T[c2 * 512 + lane + 64];
        wg0[c2] = w_ih_T[c2 * 512 + lane + 256];
        wg1[c2] = w_ih_T[c2 * 512 + lane + 320];
        wo0[c2] = w_ih_T[c2 * 512 + lane + 384];
        wo1[c2] = w_ih_T[c2 * 512 + lane + 448];
    }
    float bi0 = biassum[lane],       bi1 = biassum[lane + 64];
    float bg0 = biassum[lane + 256], bg1 = biassum[lane + 320];
    float bo0 = biassum[lane + 384], bo1 = biassum[lane + 448];
    for (int ii = w; ii < nn; ii += 4) {
        int idx = l_idx[ii];
        int len = l_len[ii];
        int n = l_ev0[ii];
        float f = 0.f;
        if (lane < 16) f = features[((size_t)(bb * N + n)) * C + lane];
        float ai0 = bi0, ai1 = bi1, ag0 = bg0, ag1 = bg1, ao0 = bo0, ao1 = bo1;
#pragma unroll
        for (int c2 = 0; c2 < 16; c2++) {
            float xv = __shfl(f, c2, 64);
            ai0 += wi0[c2] * xv; ai1 += wi1[c2] * xv;
            ag0 += wg0[c2] * xv; ag1 += wg1[c2] * xv;
            ao0 += wo0[c2] * xv; ao1 += wo1[c2] * xv;
        }
        float c0 = sigf(ai0) * tanhf(ag0);
        float c1 = sigf(ai1) * tanhf(ag1);
        float h0 = sigf(ao0) * tanhf(c0);
        float h1 = sigf(ao1) * tanhf(c1);
        hfin[(size_t)idx * HID + lane] = h0;
        hfin[(size_t)idx * HID + lane + 64] = h1;
        if (len >= 2) {
            cfin[(size_t)idx * HID + lane] = c0;
            cfin[(size_t)idx * HID + lane + 64] = c1;
        }
    }
}

// ---------------- step2: batched second step for all len>=2 chains ---------
// 8 chains per 256-thread block; thread = 2 gate cols; each w_hh row loaded
// once, reused x8 chains (R5 lesson: no giant per-thread register cache).
__global__ __launch_bounds__(256) void k_step2(
    const float* __restrict__ features, const float* __restrict__ w_ih_T,
    const float* __restrict__ w_hh_T, const float* __restrict__ biassum,
    const int* __restrict__ chainrf, const int* __restrict__ cntrf,
    const int* __restrict__ slots, const int* __restrict__ m2cnt,
    const int* __restrict__ mlist2, float* __restrict__ hfin,
    float* __restrict__ cfin) {
    int tid = threadIdx.x;
    __shared__ float hs[128][8];      // h_prev, k-major rows (32B aligned)
    __shared__ float xs[8][16];
    __shared__ float gl[8][512];      // gates
    __shared__ int c_idx[8], c_ev1[8], c_len[8];
    float wi0[16], wi1[16];
#pragma unroll
    for (int c2 = 0; c2 < 16; c2++) {
        wi0[c2] = w_ih_T[c2 * 512 + tid];
        wi1[c2] = w_ih_T[c2 * 512 + tid + 256];
    }
    float b0 = biassum[tid], b1 = biassum[tid + 256];
    for (int bb = 0; bb < B; bb++) {
        int Mb = m2cnt[bb * 16]; if (Mb > 256) Mb = 256;
        int nch = (Mb + 7) >> 3;
        for (int ch = blockIdx.x; ch < nch; ch += gridDim.x) {
            int base = ch * 8;
            if (tid < 8) {
                int e = base + tid;
                int idx = (e < Mb) ? mlist2[bb * 256 + e] : -1;
                c_idx[tid] = idx;
                if (idx >= 0) {
                    int bn = bb * NRF + chainrf[idx];
                    c_ev1[tid] = slots[(size_t)bn * MAXLEN + 1];
                    int len = cntrf[bn];
                    c_len[tid] = (len > MAXLEN) ? MAXLEN : len;
                }
            }
            __syncthreads();
            {   // stage h_prev: thread -> (i = tid&7, k = tid>>3 + 32r)
                int i = tid & 7, k0 = tid >> 3;
#pragma unroll
                for (int r = 0; r < 4; r++) {
                    int k = k0 + 32 * r;
                    int idx = c_idx[i];
                    hs[k][i] = (idx >= 0) ? hfin[(size_t)idx * HID + k] : 0.f;
                }
                if (tid < 128) {      // stage x: i = tid>>4, c = tid&15
                    int i2 = tid >> 4, cc = tid & 15;
                    if (c_idx[i2] >= 0)
                        xs[i2][cc] = features[((size_t)(bb * N + c_ev1[i2])) * C + cc];
                }
            }
            __syncthreads();
            float a0[8], a1[8];
#pragma unroll
            for (int i = 0; i < 8; i++) { a0[i] = b0; a1[i] = b1; }
#pragma unroll
            for (int c2 = 0; c2 < 16; c2++) {
#pragma unroll
                for (int i = 0; i < 8; i++) {
                    float xv = xs[i][c2];
                    a0[i] += wi0[c2] * xv;
                    a1[i] += wi1[c2] * xv;
                }
            }
#pragma unroll 4
            for (int k = 0; k < 128; k++) {
                float wh0 = w_hh_T[k * 512 + tid];
                float wh1 = w_hh_T[k * 512 + tid + 256];
                const float4 h03 = *(const float4*)&hs[k][0];
                const float4 h47 = *(const float4*)&hs[k][4];
                a0[0] += wh0 * h03.x; a1[0] += wh1 * h03.x;
                a0[1] += wh0 * h03.y; a1[1] += wh1 * h03.y;
                a0[2] += wh0 * h03.z; a1[2] += wh1 * h03.z;
                a0[3] += wh0 * h03.w; a1[3] += wh1 * h03.w;
                a0[4] += wh0 * h47.x; a1[4] += wh1 * h47.x;
                a0[5] += wh0 * h47.y; a1[5] += wh1 * h47.y;
                a0[6] += wh0 * h47.z; a1[6] += wh1 * h47.z;
                a0[7] += wh0 * h47.w; a1[7] += wh1 * h47.w;
            }
#pragma unroll
            for (int i = 0; i < 8; i++) {
                gl[i][tid] = a0[i];
                gl[i][tid + 256] = a1[i];
            }
            __syncthreads();
            if (tid < 128) {
#pragma unroll
                for (int i = 0; i < 8; i++) {
                    int idx = c_idx[i];
                    if (idx < 0) continue;
                    float cp = cfin[(size_t)idx * HID + tid];
                    float ig = sigf(gl[i][tid]);
                    float fg = sigf(gl[i][tid + 128]);
                    float gg = tanhf(gl[i][tid + 256]);
                    float og = sigf(gl[i][tid + 384]);
                    float cn = fg * cp + ig * gg;
                    hfin[(size_t)idx * HID + tid] = og * tanhf(cn);
                    cfin[(size_t)idx * HID + tid] = cn;   // for len>=3
                }
            }
            __syncthreads();   // before LDS reuse
        }
    }
}

// ---------------- tail: len>=3 chains (~45 total), one block per chain -----
__global__ __launch_bounds__(256) void k_tail(
    const float* __restrict__ features, const float* __restrict__ w_ih_T,
    const float* __restrict__ w_hh_T, const float* __restrict__ biassum,
    const int* __restrict__ chainrf, const int* __restrict__ cntrf,
    const int* __restrict__ slots, const int* __restrict__ m3cnt,
    const int* __restrict__ mlist3, float* __restrict__ hfin,
    float* __restrict__ cfin) {
    int tid = threadIdx.x;
    __shared__ float h_s[HID];
    __shared__ float g_s[512];
    __shared__ float x_s[16];
    float wi0[16], wi1[16];
#pragma unroll
    for (int c2 = 0; c2 < 16; c2++) {
        wi0[c2] = w_ih_T[c2 * 512 + tid];
        wi1[c2] = w_ih_T[c2 * 512 + tid + 256];
    }
    float b0 = biassum[tid], b1 = biassum[tid + 256];
    for (int bb = 0; bb < B; bb++) {
        int Mb = m3cnt[bb * 16]; if (Mb > 64) Mb = 64;
        for (int m = blockIdx.x; m < Mb; m += gridDim.x) {
            int idx = mlist3[bb * 64 + m];
            int bn = bb * NRF + chainrf[idx];
            int len = cntrf[bn];
            if (len > MAXLEN) len = MAXLEN;
            if (tid < 128) h_s[tid] = hfin[(size_t)idx * HID + tid];
            float cl = (tid < 128) ? cfin[(size_t)idx * HID + tid] : 0.f;
            for (int t = 2; t < len; t++) {
                int n = slots[(size_t)bn * MAXLEN + t];   // uniform scalar
                if (tid < 16) x_s[tid] = features[((size_t)(bb * N + n)) * C + tid];
                __syncthreads();
                float a0 = b0, a1 = b1;
#pragma unroll
                for (int c2 = 0; c2 < 16; c2++) {
                    a0 += wi0[c2] * x_s[c2];
                    a1 += wi1[c2] * x_s[c2];
                }
#pragma unroll 4
                for (int k = 0; k < 128; k++) {
                    float hv = h_s[k];
                    a0 += w_hh_T[k * 512 + tid] * hv;
                    a1 += w_hh_T[k * 512 + tid + 256] * hv;
                }
                g_s[tid] = a0;
                g_s[tid + 256] = a1;
                __syncthreads();
                if (tid < 128) {
                    float ig = sigf(g_s[tid]);
                    float fg = sigf(g_s[tid + 128]);
                    float gg = tanhf(g_s[tid + 256]);
                    float og = sigf(g_s[tid + 384]);
                    cl = fg * cl + ig * gg;
                    h_s[tid] = og * tanhf(cl);
                }
                __syncthreads();
            }
            if (tid < 128) hfin[(size_t)idx * HID + tid] = h_s[tid];
            __syncthreads();   // before h_s reuse
        }
    }
}

// ---------------- scatter to dense [B, HID, 128, 128] ----------------
__global__ __launch_bounds__(256) void k_scatter(
    const float* __restrict__ hfin, const int* __restrict__ map,
    float* __restrict__ out) {
    int b = blockIdx.x >> 7;        // grid = B*128
    int y = blockIdx.x & 127;
    int t = threadIdx.x;
    int xq = t & 31;                // x quad: covers x = 4*xq .. 4*xq+3
    int hg = t >> 5;                // hid group 0..7 (16 hids each)
    const int4* mrow = (const int4*)(map + b * NRF + y * 128);
    int4 kk = mrow[xq];
    const float* hb = hfin + (size_t)b * MAXCH * HID;
#pragma unroll
    for (int hh = 0; hh < 16; hh++) {
        int hid = hg * 16 + hh;
        float4 v;
        v.x = (kk.x < 0) ? 0.f : hb[kk.x * HID + hid];
        v.y = (kk.y < 0) ? 0.f : hb[kk.y * HID + hid];
        v.z = (kk.z < 0) ? 0.f : hb[kk.z * HID + hid];
        v.w = (kk.w < 0) ? 0.f : hb[kk.w * HID + hid];
        *(float4*)(out + ((((size_t)b * HID + hid) * 128 + y) * 128) + xq * 4) = v;
    }
}

extern "C" void kernel_launch(void* const* d_in, const int* in_sizes, int n_in,
                              void* d_out, int out_size, void* d_ws, size_t ws_size,
                              hipStream_t stream) {
    const float* features = (const float*)d_in[0];   // [B,N,C] f32
    const int*   coords   = (const int*)d_in[1];     // [B,N,2] i32
    const float* w_ih     = (const float*)d_in[2];   // [512,16]
    const float* w_hh     = (const float*)d_in[3];   // [512,128]
    const float* b_ih     = (const float*)d_in[4];   // [512]
    const float* b_hh     = (const float*)d_in[5];   // [512]
    float* out = (float*)d_out;                      // [B,128,128,128]

    char* ws = (char*)d_ws;
    float* w_ih_T  = (float*)(ws + 0);               //    32768 B
    float* w_hh_T  = (float*)(ws + 32768);           //   262144 B
    float* biassum = (float*)(ws + 294912);          //     2048 B
    int*   cntrf   = (int*)(ws + 296960);            //   524288 B
    int*   map     = (int*)(ws + 821248);            //   524288 B
    int*   cnt     = (int*)(ws + 1345536);           //       64 B
    int*   chainrf = (int*)(ws + 1345600);           //    65536 B
    int*   slots   = (int*)(ws + 1411136);           //  4194304 B
    float* hfin    = (float*)(ws + 5605440);         //  8388608 B
    float* cfin    = (float*)(ws + 13994048);        //  8388608 B
    int*   m2cnt   = (int*)(ws + 22382656);          //      512 B (stride 16)
    int*   mlist2  = (int*)(ws + 22383168);          //     8192 B
    int*   m3cnt   = (int*)(ws + 22391360);          //      512 B (stride 16)
    int*   mlist3  = (int*)(ws + 22391872);          //     2048 B  -> ~22.4 MB

    k_setup<<<dim3(B * NRF / 256), dim3(256), 0, stream>>>(
        w_ih, w_hh, b_ih, b_hh, w_ih_T, w_hh_T, biassum, cntrf, map, cnt,
        m2cnt, m3cnt);
    k_build<<<dim3(B * N / 256), dim3(256), 0, stream>>>(
        coords, cntrf, map, cnt, chainrf, slots);
    k_first<<<dim3(B * MAXCH / 64), dim3(256), 0, stream>>>(
        features, w_ih_T, biassum, cnt, chainrf, cntrf, slots, hfin, cfin,
        m2cnt, mlist2, m3cnt, mlist3);
    k_step2<<<dim3(128), dim3(256), 0, stream>>>(
        features, w_ih_T, w_hh_T, biassum, chainrf, cntrf, slots,
        m2cnt, mlist2, hfin, cfin);
    k_tail<<<dim3(64), dim3(256), 0, stream>>>(
        features, w_ih_T, w_hh_T, biassum, chainrf, cntrf, slots,
        m3cnt, mlist3, hfin, cfin);
    k_scatter<<<dim3(B * 128), dim3(256), 0, stream>>>(hfin, map, out);
}

// Round 7
// 142.470 us; speedup vs baseline: 1.9726x; 1.9726x over previous
//
#include <hip/hip_runtime.h>
#include <hip/hip_bf16.h>
#include <math.h>

#define B 8
#define N 2048
#define C 16
#define HID 128
#define NRF 16384      // 128*128
#define MAXLEN 8
#define MAXCH 2048     // max chains per batch (<= N)

__device__ __forceinline__ float sigf(float x) { return 1.f / (1.f + expf(-x)); }

// ---------------- setup: init counters + transpose weights + bias ----------
__global__ __launch_bounds__(256) void k_setup(
    const float* __restrict__ w_ih, const float* __restrict__ w_hh,
    const float* __restrict__ b_ih, const float* __restrict__ b_hh,
    float* __restrict__ w_ih_T, float* __restrict__ w_hh_T,
    float* __restrict__ biassum, int* __restrict__ cntrf,
    int* __restrict__ map, int* __restrict__ cnt, int* __restrict__ m2cnt) {
    int i = blockIdx.x * blockDim.x + threadIdx.x;   // 512 blocks -> B*NRF
    cntrf[i] = 0;
    map[i] = -1;
    if (i < B) cnt[i] = 0;
    if (i < 128) m2cnt[i] = 0;
    if (i < C * 512) {                 // w_ih_T[c][j] = w_ih[j][c]
        int c = i >> 9, j = i & 511;
        w_ih_T[i] = w_ih[j * C + c];
    }
    if (i < HID * 512) {               // w_hh_T[k][j] = w_hh[j][k]
        int k = i >> 9, j = i & 511;
        w_hh_T[i] = w_hh[j * HID + k];
    }
    if (i < 512) biassum[i] = b_ih[i] + b_hh[i];
}

// ---------------- build: bucket events by (b, rf) ----------------
// R1 lesson: ONE device atomic on cnt[b] per block (contended same-address
// atomics ~98 ns each).
__global__ __launch_bounds__(256) void k_build(
    const int* __restrict__ coords, int* __restrict__ cntrf,
    int* __restrict__ map, int* __restrict__ cnt,
    int* __restrict__ chainrf, int* __restrict__ slots) {
    int tid = threadIdx.x;
    int idx = blockIdx.x * 256 + tid;   // grid exactly B*N (64 blocks)
    int b = idx >> 11;                  // uniform within block
    int n = idx & (N - 1);
    int x = coords[idx * 2 + 0];
    int y = coords[idx * 2 + 1];
    int rf = y * 128 + x;
    int pos = atomicAdd(&cntrf[b * NRF + rf], 1);
    if (pos < MAXLEN) slots[(b * NRF + rf) * MAXLEN + pos] = n;
    __shared__ int lcnt, lbase;
    if (tid == 0) lcnt = 0;
    __syncthreads();
    int r = -1;
    if (pos == 0) r = atomicAdd(&lcnt, 1);
    __syncthreads();
    if (tid == 0) lbase = atomicAdd(&cnt[b], lcnt);   // 1 per block
    __syncthreads();
    if (pos == 0) {
        int k = lbase + r;
        chainrf[b * MAXCH + k] = rf;
        map[b * NRF + rf] = k;
    }
}

// ---------------- phase0: step-0 for EVERY chain + multi-chain list --------
// c_prev = 0 -> f-gate dead. Writes h always, c only for len>=2. Sorts slots
// into time order for multi chains. Per-batch multi lists (32 blocks contend
// per counter, ~3 us bounded).
__global__ __launch_bounds__(256) void k_phase0(
    const float* __restrict__ features, const float* __restrict__ w_ih_T,
    const float* __restrict__ biassum, const int* __restrict__ cnt,
    const int* __restrict__ chainrf, const int* __restrict__ cntrf,
    int* __restrict__ slots, float* __restrict__ hfin, float* __restrict__ cfin,
    int* __restrict__ m2cnt, int* __restrict__ mlist2) {
    int tid = threadIdx.x;
    int lane = tid & 63, w = tid >> 6;
    int bb = blockIdx.x >> 5;           // 32 blocks per batch, grid = 256
    __shared__ int l_idx[64], l_len[64], l_ev0[64];
    __shared__ int lm2[64];
    __shared__ int l_n, l_m2, l_b2;
    if (tid == 0) { l_n = 0; l_m2 = 0; }
    __syncthreads();
    if (tid < 64) {                     // parallel slot scan
        int idx = blockIdx.x * 64 + tid;
        int j = idx & (MAXCH - 1);
        if (j < cnt[bb]) {
            int bn = bb * NRF + chainrf[idx];
            int len = cntrf[bn];
            if (len > MAXLEN) len = MAXLEN;
            int* sl = slots + (size_t)bn * MAXLEN;
            int ev0;
            if (len >= 2) {             // time-sort slots, write back
                int ev[MAXLEN];
#pragma unroll
                for (int t = 0; t < MAXLEN; t++) {
                    int v = sl[t];
                    ev[t] = (t < len) ? v : 0x7fffffff;
                }
#pragma unroll
                for (int a = 0; a < MAXLEN; a++)
#pragma unroll
                    for (int q = 0; q < MAXLEN - 1; q++) {
                        int u = ev[q], v = ev[q + 1];
                        ev[q] = min(u, v);
                        ev[q + 1] = max(u, v);
                    }
                for (int t = 0; t < len; t++) sl[t] = ev[t];
                ev0 = ev[0];
                int r2 = atomicAdd(&l_m2, 1);
                lm2[r2] = idx;
            } else {
                ev0 = sl[0];
            }
            int r = atomicAdd(&l_n, 1);
            l_idx[r] = idx; l_len[r] = len; l_ev0[r] = ev0;
        }
    }
    __syncthreads();
    if (tid == 0 && l_m2 > 0) l_b2 = atomicAdd(&m2cnt[bb * 16], l_m2);
    __syncthreads();
    if (tid < l_m2) { int p = l_b2 + tid; if (p < 256) mlist2[bb * 256 + p] = lm2[tid]; }
    int nn = l_n;
    if (nn == 0) return;
    // register-cache the 6 live gate columns of w_ih_T (f dead at step 0)
    float wi0[16], wi1[16], wg0[16], wg1[16], wo0[16], wo1[16];
#pragma unroll
    for (int c2 = 0; c2 < 16; c2++) {
        wi0[c2] = w_ih_T[c2 * 512 + lane];
        wi1[c2] = w_ih_T[c2 * 512 + lane + 64];
        wg0[c2] = w_ih_T[c2 * 512 + lane + 256];
        wg1[c2] = w_ih_T[c2 * 512 + lane + 320];
        wo0[c2] = w_ih_T[c2 * 512 + lane + 384];
        wo1[c2] = w_ih_T[c2 * 512 + lane + 448];
    }
    float bi0 = biassum[lane],       bi1 = biassum[lane + 64];
    float bg0 = biassum[lane + 256], bg1 = biassum[lane + 320];
    float bo0 = biassum[lane + 384], bo1 = biassum[lane + 448];
    for (int ii = w; ii < nn; ii += 4) {
        int idx = l_idx[ii];
        int len = l_len[ii];
        int n = l_ev0[ii];
        float f = 0.f;
        if (lane < 16) f = features[((size_t)(bb * N + n)) * C + lane];
        float ai0 = bi0, ai1 = bi1, ag0 = bg0, ag1 = bg1, ao0 = bo0, ao1 = bo1;
#pragma unroll
        for (int c2 = 0; c2 < 16; c2++) {
            float xv = __shfl(f, c2, 64);
            ai0 += wi0[c2] * xv; ai1 += wi1[c2] * xv;
            ag0 += wg0[c2] * xv; ag1 += wg1[c2] * xv;
            ao0 += wo0[c2] * xv; ao1 += wo1[c2] * xv;
        }
        float c0 = sigf(ai0) * tanhf(ag0);
        float c1 = sigf(ai1) * tanhf(ag1);
        float h0 = sigf(ao0) * tanhf(c0);
        float h1 = sigf(ao1) * tanhf(c1);
        hfin[(size_t)idx * HID + lane] = h0;
        hfin[(size_t)idx * HID + lane + 64] = h1;
        if (len >= 2) {
            cfin[(size_t)idx * HID + lane] = c0;
            cfin[(size_t)idx * HID + lane + 64] = c1;
        }
    }
}

// ---------------- recur: ONE 512-thread block per multi chain --------------
// R6 lesson: never serialize batches/chains inside few blocks. 1024 blocks
// (batch = blockIdx>>7, slot = blockIdx&127); with ~118 multi chains per
// batch every chain gets its own block, all ~950 run concurrently
// (4 blocks/CU, full 32 waves/CU). Thread = 1 gate column: per step
// 128 coalesced L2 loads of w_hh_T + 128 FMAs, h broadcast from LDS.
__global__ __launch_bounds__(512) void k_recur(
    const float* __restrict__ features, const float* __restrict__ w_ih_T,
    const float* __restrict__ w_hh_T, const float* __restrict__ biassum,
    const int* __restrict__ chainrf, const int* __restrict__ cntrf,
    const int* __restrict__ slots, const int* __restrict__ m2cnt,
    const int* __restrict__ mlist2, float* __restrict__ hfin,
    const float* __restrict__ cfin) {
    int tid = threadIdx.x;
    int bb = blockIdx.x >> 7;           // 8 batches x 128 slots
    int j0 = blockIdx.x & 127;
    int Mb = m2cnt[bb * 16]; if (Mb > 256) Mb = 256;
    if (j0 >= Mb) return;
    __shared__ float h_s[HID];
    __shared__ float x_s[16];
    __shared__ float g_s[512];
    float wi[16];
#pragma unroll
    for (int c2 = 0; c2 < 16; c2++) wi[c2] = w_ih_T[c2 * 512 + tid];
    float bsum = biassum[tid];
    for (int j = j0; j < Mb; j += 128) {   // typically exactly 1 iteration
        int idx = mlist2[bb * 256 + j];
        int bn = bb * NRF + chainrf[idx];
        int len = cntrf[bn];
        if (len > MAXLEN) len = MAXLEN;
        const int* sl = slots + (size_t)bn * MAXLEN;   // time-sorted
        if (tid < 128) h_s[tid] = hfin[(size_t)idx * HID + tid];
        float c = (tid < 128) ? cfin[(size_t)idx * HID + tid] : 0.f;
        __syncthreads();                   // h_s visible
        for (int t = 1; t < len; t++) {    // len block-uniform
            int n = sl[t];
            if (tid < 16) x_s[tid] = features[((size_t)(bb * N + n)) * C + tid];
            __syncthreads();               // x_s ready (h_s from prev sync)
            float a0 = bsum, a1 = 0.f, a2 = 0.f, a3 = 0.f;
#pragma unroll
            for (int c2 = 0; c2 < 16; c2++) a0 += wi[c2] * x_s[c2];
#pragma unroll 8
            for (int k = 0; k < 128; k += 4) {
                a0 += w_hh_T[k * 512 + tid] * h_s[k];
                a1 += w_hh_T[(k + 1) * 512 + tid] * h_s[k + 1];
                a2 += w_hh_T[(k + 2) * 512 + tid] * h_s[k + 2];
                a3 += w_hh_T[(k + 3) * 512 + tid] * h_s[k + 3];
            }
            g_s[tid] = (a0 + a1) + (a2 + a3);
            __syncthreads();
            if (tid < 128) {
                float ig = sigf(g_s[tid]);
                float fg = sigf(g_s[tid + 128]);
                float gg = tanhf(g_s[tid + 256]);
                float og = sigf(g_s[tid + 384]);
                c = fg * c + ig * gg;
                h_s[tid] = og * tanhf(c);
            }
            __syncthreads();
        }
        if (tid < 128) hfin[(size_t)idx * HID + tid] = h_s[tid];
        __syncthreads();                   // before h_s reuse by next j
    }
}

// ---------------- scatter to dense [B, HID, 128, 128] ----------------
__global__ __launch_bounds__(256) void k_scatter(
    const float* __restrict__ hfin, const int* __restrict__ map,
    float* __restrict__ out) {
    int b = blockIdx.x >> 7;        // grid = B*128
    int y = blockIdx.x & 127;
    int t = threadIdx.x;
    int xq = t & 31;                // x quad: covers x = 4*xq .. 4*xq+3
    int hg = t >> 5;                // hid group 0..7 (16 hids each)
    const int4* mrow = (const int4*)(map + b * NRF + y * 128);
    int4 kk = mrow[xq];
    const float* hb = hfin + (size_t)b * MAXCH * HID;
#pragma unroll
    for (int hh = 0; hh < 16; hh++) {
        int hid = hg * 16 + hh;
        float4 v;
        v.x = (kk.x < 0) ? 0.f : hb[kk.x * HID + hid];
        v.y = (kk.y < 0) ? 0.f : hb[kk.y * HID + hid];
        v.z = (kk.z < 0) ? 0.f : hb[kk.z * HID + hid];
        v.w = (kk.w < 0) ? 0.f : hb[kk.w * HID + hid];
        *(float4*)(out + ((((size_t)b * HID + hid) * 128 + y) * 128) + xq * 4) = v;
    }
}

extern "C" void kernel_launch(void* const* d_in, const int* in_sizes, int n_in,
                              void* d_out, int out_size, void* d_ws, size_t ws_size,
                              hipStream_t stream) {
    const float* features = (const float*)d_in[0];   // [B,N,C] f32
    const int*   coords   = (const int*)d_in[1];     // [B,N,2] i32
    const float* w_ih     = (const float*)d_in[2];   // [512,16]
    const float* w_hh     = (const float*)d_in[3];   // [512,128]
    const float* b_ih     = (const float*)d_in[4];   // [512]
    const float* b_hh     = (const float*)d_in[5];   // [512]
    float* out = (float*)d_out;                      // [B,128,128,128]

    char* ws = (char*)d_ws;
    float* w_ih_T  = (float*)(ws + 0);               //    32768 B
    float* w_hh_T  = (float*)(ws + 32768);           //   262144 B
    float* biassum = (float*)(ws + 294912);          //     2048 B
    int*   cntrf   = (int*)(ws + 296960);            //   524288 B
    int*   map     = (int*)(ws + 821248);            //   524288 B
    int*   cnt     = (int*)(ws + 1345536);           //       64 B
    int*   chainrf = (int*)(ws + 1345600);           //    65536 B
    int*   slots   = (int*)(ws + 1411136);           //  4194304 B
    float* hfin    = (float*)(ws + 5605440);         //  8388608 B
    float* cfin    = (float*)(ws + 13994048);        //  8388608 B
    int*   m2cnt   = (int*)(ws + 22382656);          //      512 B (stride 16)
    int*   mlist2  = (int*)(ws + 22383168);          //     8192 B -> ~22.4 MB

    k_setup<<<dim3(B * NRF / 256), dim3(256), 0, stream>>>(
        w_ih, w_hh, b_ih, b_hh, w_ih_T, w_hh_T, biassum, cntrf, map, cnt, m2cnt);
    k_build<<<dim3(B * N / 256), dim3(256), 0, stream>>>(
        coords, cntrf, map, cnt, chainrf, slots);
    k_phase0<<<dim3(B * MAXCH / 64), dim3(256), 0, stream>>>(
        features, w_ih_T, biassum, cnt, chainrf, cntrf, slots, hfin, cfin,
        m2cnt, mlist2);
    k_recur<<<dim3(B * 128), dim3(512), 0, stream>>>(
        features, w_ih_T, w_hh_T, biassum, chainrf, cntrf, slots,
        m2cnt, mlist2, hfin, cfin);
    k_scatter<<<dim3(B * 128), dim3(256), 0, stream>>>(hfin, map, out);
}

// Round 8
// 132.864 us; speedup vs baseline: 2.1152x; 1.0723x over previous
//
#include <hip/hip_runtime.h>
#include <hip/hip_bf16.h>
#include <math.h>

#define B 8
#define N 2048
#define C 16
#define HID 128
#define NRF 16384      // 128*128
#define MAXLEN 8
#define MAXCH 2048     // max chains per batch (<= N)

__device__ __forceinline__ float sigf(float x) { return 1.f / (1.f + expf(-x)); }

// ---------------- pre: per-batch build (LDS counters) + weight transpose ---
// Blocks 0..7: one batch each, 1024 threads, cntrf in LDS (64 KB) -> no
// global init dependency, no cross-block atomics at all (R0/R1 lesson made
// structural). Emits compact chainlen + multi list per batch.
// Blocks 8..80: weight transpose + bias (independent work, same dispatch).
__global__ __launch_bounds__(1024) void k_pre(
    const int* __restrict__ coords, const float* __restrict__ w_ih,
    const float* __restrict__ w_hh, const float* __restrict__ b_ih,
    const float* __restrict__ b_hh, float* __restrict__ w_ih_T,
    float* __restrict__ w_hh_T, float* __restrict__ biassum,
    int* __restrict__ map, int* __restrict__ cnt, int* __restrict__ chainrf,
    int* __restrict__ chainlen, int* __restrict__ slots,
    int* __restrict__ m2cnt, int* __restrict__ mlist2) {
    int tid = threadIdx.x;
    if (blockIdx.x < 8) {
        int bb = blockIdx.x;
        __shared__ int cnt_l[NRF];          // 64 KB
        __shared__ int nch_l, nmul_l;
#pragma unroll
        for (int i = 0; i < 16; i++) cnt_l[tid + 1024 * i] = 0;
        if (tid == 0) { nch_l = 0; nmul_l = 0; }
#pragma unroll
        for (int i = 0; i < 16; i++) map[bb * NRF + tid + 1024 * i] = -1;
        __syncthreads();
        int n0 = tid, n1 = tid + 1024;
        int2 c0 = ((const int2*)coords)[bb * N + n0];
        int2 c1 = ((const int2*)coords)[bb * N + n1];
        int rf0 = c0.y * 128 + c0.x;
        int rf1 = c1.y * 128 + c1.x;
        int pos0 = atomicAdd(&cnt_l[rf0], 1);
        int pos1 = atomicAdd(&cnt_l[rf1], 1);
        if (pos0 < MAXLEN) slots[((size_t)bb * NRF + rf0) * MAXLEN + pos0] = n0;
        if (pos1 < MAXLEN) slots[((size_t)bb * NRF + rf1) * MAXLEN + pos1] = n1;
        __syncthreads();                    // counts final
#pragma unroll
        for (int e = 0; e < 2; e++) {
            int rf = e ? rf1 : rf0;
            int pos = e ? pos1 : pos0;
            if (pos == 0) {                 // chain head registers chain
                int j = atomicAdd(&nch_l, 1);            // LDS atomic
                int len = cnt_l[rf];
                if (len > MAXLEN) len = MAXLEN;
                chainrf[bb * MAXCH + j] = rf;
                chainlen[bb * MAXCH + j] = len;
                map[bb * NRF + rf] = j;
                if (len >= 2) {
                    int m = atomicAdd(&nmul_l, 1);
                    if (m < 256) mlist2[bb * 256 + m] = bb * MAXCH + j;
                }
            }
        }
        __syncthreads();
        if (tid == 0) {
            cnt[bb] = nch_l;
            m2cnt[bb * 16] = (nmul_l > 256) ? 256 : nmul_l;
        }
    } else {
        int i = (blockIdx.x - 8) * 1024 + tid;   // 73 blocks cover 74240
        if (i < C * 512) {                 // w_ih_T[c][j] = w_ih[j][c]
            int c = i >> 9, j = i & 511;
            w_ih_T[i] = w_ih[j * C + c];
        }
        if (i < HID * 512) {               // w_hh_T[k][j] = w_hh[j][k]
            int k = i >> 9, j = i & 511;
            w_hh_T[i] = w_hh[j * HID + k];
        }
        if (i < 512) biassum[i] = b_ih[i] + b_hh[i];
    }
}

// ---------------- phase0: step-0 for EVERY chain (c_prev=0, f-gate dead) ---
// R7 lesson: 256 blocks = 1 block/CU left every dependent load exposed.
// Now 2048 blocks (8 slots/block, 2 chains/wave), w_ih_T staged in LDS.
// Also time-sorts multi-chain slots (event index IS time order).
__global__ __launch_bounds__(256) void k_phase0(
    const float* __restrict__ features, const float* __restrict__ w_ih_T,
    const float* __restrict__ biassum, const int* __restrict__ cnt,
    const int* __restrict__ chainrf, const int* __restrict__ chainlen,
    int* __restrict__ slots, float* __restrict__ hfin,
    float* __restrict__ cfin) {
    int tid = threadIdx.x;
    int bb = blockIdx.x >> 8;              // 256 blocks per batch
    int slot0 = (blockIdx.x & 255) * 8;
    __shared__ float ls_w[C * 512];        // 32 KB
    __shared__ float ls_b[512];
    __shared__ int l_idx[8], l_len[8], l_ev0[8];
    int nc = cnt[bb];
    if (tid < 8) {
        int j = slot0 + tid;
        int idx = bb * MAXCH + j;
        if (j < nc) {
            int len = chainlen[idx];
            int* sl = slots + ((size_t)bb * NRF + chainrf[idx]) * MAXLEN;
            int ev0;
            if (len >= 2) {                // time-sort, write back
                int ev[MAXLEN];
#pragma unroll
                for (int t = 0; t < MAXLEN; t++) {
                    int v = sl[t];
                    ev[t] = (t < len) ? v : 0x7fffffff;
                }
#pragma unroll
                for (int a = 0; a < MAXLEN; a++)
#pragma unroll
                    for (int q = 0; q < MAXLEN - 1; q++) {
                        int u = ev[q], v = ev[q + 1];
                        ev[q] = min(u, v);
                        ev[q + 1] = max(u, v);
                    }
                for (int t = 0; t < len; t++) sl[t] = ev[t];
                ev0 = ev[0];
            } else {
                ev0 = sl[0];
            }
            l_idx[tid] = idx; l_len[tid] = len; l_ev0[tid] = ev0;
        } else {
            l_idx[tid] = -1;
        }
    }
    for (int i = tid; i < C * 512; i += 256) ls_w[i] = w_ih_T[i];
    ls_b[tid] = biassum[tid];
    ls_b[tid + 256] = biassum[tid + 256];
    __syncthreads();
    int w = tid >> 6, lane = tid & 63;
#pragma unroll
    for (int s2 = 0; s2 < 2; s2++) {
        int s = 2 * w + s2;
        int idx = l_idx[s];
        if (idx < 0) continue;
        int len = l_len[s];
        int n = l_ev0[s];
        float f = 0.f;
        if (lane < 16) f = features[((size_t)(bb * N + n)) * C + lane];
        float ai0 = ls_b[lane],       ai1 = ls_b[lane + 64];
        float ag0 = ls_b[lane + 256], ag1 = ls_b[lane + 320];
        float ao0 = ls_b[lane + 384], ao1 = ls_b[lane + 448];
#pragma unroll
        for (int c2 = 0; c2 < 16; c2++) {
            float xv = __shfl(f, c2, 64);
            ai0 += ls_w[c2 * 512 + lane]       * xv;
            ai1 += ls_w[c2 * 512 + lane + 64]  * xv;
            ag0 += ls_w[c2 * 512 + lane + 256] * xv;
            ag1 += ls_w[c2 * 512 + lane + 320] * xv;
            ao0 += ls_w[c2 * 512 + lane + 384] * xv;
            ao1 += ls_w[c2 * 512 + lane + 448] * xv;
        }
        float c0 = sigf(ai0) * tanhf(ag0);
        float c1 = sigf(ai1) * tanhf(ag1);
        float h0 = sigf(ao0) * tanhf(c0);
        float h1 = sigf(ao1) * tanhf(c1);
        hfin[(size_t)idx * HID + lane] = h0;
        hfin[(size_t)idx * HID + lane + 64] = h1;
        if (len >= 2) {
            cfin[(size_t)idx * HID + lane] = c0;
            cfin[(size_t)idx * HID + lane + 64] = c1;
        }
    }
}

// ---------------- recur: ONE 512-thread block per multi chain --------------
// R6 lesson: never serialize chains inside few blocks. 1024 blocks; every
// multi chain gets its own block, all ~950 run concurrently. Thread = 1 gate
// column: per step 128 coalesced L2 loads of w_hh_T + 128 FMAs, h broadcast
// from LDS.
__global__ __launch_bounds__(512) void k_recur(
    const float* __restrict__ features, const float* __restrict__ w_ih_T,
    const float* __restrict__ w_hh_T, const float* __restrict__ biassum,
    const int* __restrict__ chainrf, const int* __restrict__ chainlen,
    const int* __restrict__ slots, const int* __restrict__ m2cnt,
    const int* __restrict__ mlist2, float* __restrict__ hfin,
    const float* __restrict__ cfin) {
    int tid = threadIdx.x;
    int bb = blockIdx.x >> 7;           // 8 batches x 128 slots
    int j0 = blockIdx.x & 127;
    int Mb = m2cnt[bb * 16];
    if (j0 >= Mb) return;
    __shared__ float h_s[HID];
    __shared__ float x_s[16];
    __shared__ float g_s[512];
    float wi[16];
#pragma unroll
    for (int c2 = 0; c2 < 16; c2++) wi[c2] = w_ih_T[c2 * 512 + tid];
    float bsum = biassum[tid];
    for (int j = j0; j < Mb; j += 128) {   // typically exactly 1 iteration
        int idx = mlist2[bb * 256 + j];
        int len = chainlen[idx];
        const int* sl = slots + ((size_t)bb * NRF + chainrf[idx]) * MAXLEN;
        if (tid < 128) h_s[tid] = hfin[(size_t)idx * HID + tid];
        float c = (tid < 128) ? cfin[(size_t)idx * HID + tid] : 0.f;
        __syncthreads();                   // h_s visible
        for (int t = 1; t < len; t++) {    // len block-uniform
            int n = sl[t];
            if (tid < 16) x_s[tid] = features[((size_t)(bb * N + n)) * C + tid];
            __syncthreads();               // x_s ready
            float a0 = bsum, a1 = 0.f, a2 = 0.f, a3 = 0.f;
#pragma unroll
            for (int c2 = 0; c2 < 16; c2++) a0 += wi[c2] * x_s[c2];
#pragma unroll 8
            for (int k = 0; k < 128; k += 4) {
                a0 += w_hh_T[k * 512 + tid] * h_s[k];
                a1 += w_hh_T[(k + 1) * 512 + tid] * h_s[k + 1];
                a2 += w_hh_T[(k + 2) * 512 + tid] * h_s[k + 2];
                a3 += w_hh_T[(k + 3) * 512 + tid] * h_s[k + 3];
            }
            g_s[tid] = (a0 + a1) + (a2 + a3);
            __syncthreads();
            if (tid < 128) {
                float ig = sigf(g_s[tid]);
                float fg = sigf(g_s[tid + 128]);
                float gg = tanhf(g_s[tid + 256]);
                float og = sigf(g_s[tid + 384]);
                c = fg * c + ig * gg;
                h_s[tid] = og * tanhf(c);
            }
            __syncthreads();
        }
        if (tid < 128) hfin[(size_t)idx * HID + tid] = h_s[tid];
        __syncthreads();                   // before h_s reuse by next j
    }
}

// ---------------- scatter to dense [B, HID, 128, 128] ----------------
__global__ __launch_bounds__(256) void k_scatter(
    const float* __restrict__ hfin, const int* __restrict__ map,
    float* __restrict__ out) {
    int b = blockIdx.x >> 7;        // grid = B*128
    int y = blockIdx.x & 127;
    int t = threadIdx.x;
    int xq = t & 31;                // x quad: covers x = 4*xq .. 4*xq+3
    int hg = t >> 5;                // hid group 0..7 (16 hids each)
    const int4* mrow = (const int4*)(map + b * NRF + y * 128);
    int4 kk = mrow[xq];
    const float* hb = hfin + (size_t)b * MAXCH * HID;
#pragma unroll
    for (int hh = 0; hh < 16; hh++) {
        int hid = hg * 16 + hh;
        float4 v;
        v.x = (kk.x < 0) ? 0.f : hb[kk.x * HID + hid];
        v.y = (kk.y < 0) ? 0.f : hb[kk.y * HID + hid];
        v.z = (kk.z < 0) ? 0.f : hb[kk.z * HID + hid];
        v.w = (kk.w < 0) ? 0.f : hb[kk.w * HID + hid];
        *(float4*)(out + ((((size_t)b * HID + hid) * 128 + y) * 128) + xq * 4) = v;
    }
}

extern "C" void kernel_launch(void* const* d_in, const int* in_sizes, int n_in,
                              void* d_out, int out_size, void* d_ws, size_t ws_size,
                              hipStream_t stream) {
    const float* features = (const float*)d_in[0];   // [B,N,C] f32
    const int*   coords   = (const int*)d_in[1];     // [B,N,2] i32
    const float* w_ih     = (const float*)d_in[2];   // [512,16]
    const float* w_hh     = (const float*)d_in[3];   // [512,128]
    const float* b_ih     = (const float*)d_in[4];   // [512]
    const float* b_hh     = (const float*)d_in[5];   // [512]
    float* out = (float*)d_out;                      // [B,128,128,128]

    char* ws = (char*)d_ws;
    float* w_ih_T   = (float*)(ws + 0);              //    32768 B
    float* w_hh_T   = (float*)(ws + 32768);          //   262144 B
    float* biassum  = (float*)(ws + 294912);         //     2048 B
    int*   map      = (int*)(ws + 296960);           //   524288 B
    int*   cnt      = (int*)(ws + 821248);           //       64 B
    int*   chainrf  = (int*)(ws + 821312);           //    65536 B
    int*   chainlen = (int*)(ws + 886848);           //    65536 B
    int*   slots    = (int*)(ws + 952384);           //  4194304 B
    float* hfin     = (float*)(ws + 5146688);        //  8388608 B
    float* cfin     = (float*)(ws + 13535296);       //  8388608 B
    int*   m2cnt    = (int*)(ws + 21923904);         //      512 B (stride 16)
    int*   mlist2   = (int*)(ws + 21924416);         //     8192 B -> ~21.9 MB

    k_pre<<<dim3(81), dim3(1024), 0, stream>>>(
        coords, w_ih, w_hh, b_ih, b_hh, w_ih_T, w_hh_T, biassum,
        map, cnt, chainrf, chainlen, slots, m2cnt, mlist2);
    k_phase0<<<dim3(2048), dim3(256), 0, stream>>>(
        features, w_ih_T, biassum, cnt, chainrf, chainlen, slots, hfin, cfin);
    k_recur<<<dim3(B * 128), dim3(512), 0, stream>>>(
        features, w_ih_T, w_hh_T, biassum, chainrf, chainlen, slots,
        m2cnt, mlist2, hfin, cfin);
    k_scatter<<<dim3(B * 128), dim3(256), 0, stream>>>(hfin, map, out);
}